// Round 25
// baseline (180.023 us; speedup 1.0000x reference)
//
#include <hip/hip_runtime.h>

// GAT aggregate, FUSED (R25 = R24 + dynamic work queue): N=100000, K=16,
// D=128, DOUT=128, fp32.
// Per round, one 512-thr block (8 waves) processes one 32-node stile (two
// 16-node tiles): 2 lane-packed ctx pairs per wave (single-pass softmax,
// shift m=|self|^2, NT in-loop v-refills), bf16 hi/lo rows to dbuf LDS, ONE
// barrier, MFMA both tiles with A-fragments in registers (nt=wid).
//
// R25 change: static grid-stride (3125 stiles / 512 blocks = 6.10 -> 53
// blocks run a 7th round at ~10% machine occupancy = straggler tail ~8-15us)
// replaced by an atomicAdd work queue in d_ws (reset via hipMemsetAsync in
// the capture; harness itself enqueues memsets). Queue runs 2 stiles ahead
// so the cross-round refill pipeline is preserved; the fetch is published by
// the existing per-round barrier. Output is assignment-independent.

constexpr int K    = 16;
constexpr int D    = 128;
constexpr int DOUT = 128;
constexpr int CT_PITCH = 136;   // bf16 pitch (shorts), 272B rows

typedef short bfrag  __attribute__((ext_vector_type(8)));
typedef float afrag  __attribute__((ext_vector_type(4)));
typedef float f32x4  __attribute__((ext_vector_type(4)));   // NT-compatible 16B vector

__device__ __forceinline__ unsigned short f2bf(float f) {
    union { float f; unsigned u; } v; v.f = f;
    const unsigned r = v.u + 0x7FFF + ((v.u >> 16) & 1);   // RNE
    return (unsigned short)(r >> 16);
}
__device__ __forceinline__ float bf2f(unsigned short b) {
    union { unsigned u; float f; } v; v.u = ((unsigned)b) << 16;
    return v.f;
}

__device__ __forceinline__ f32x4 nt_load4(const float* p) {
    return __builtin_nontemporal_load((const f32x4*)p);
}

// 5-hop butterfly allreduce WITHIN each 32-lane half (off<=16 stays in-half)
__device__ __forceinline__ float half_allsum(float x) {
    #pragma unroll
    for (int off = 1; off <= 16; off <<= 1)
        x += __shfl_xor(x, off);
    return x;
}

__launch_bounds__(512, 2)
__global__ void gat_fused(const float* __restrict__ self_vecs,
                          const float* __restrict__ neigh_vecs,
                          const float* __restrict__ W,
                          float* __restrict__ out,
                          int n_stiles, int* __restrict__ qcnt) {
    // [buf][tile][plane hi/lo][row][k]  = 68 KiB
    __shared__ __align__(16) unsigned short Chl[2][2][2][16][CT_PITCH];
    __shared__ int sQ[2];   // work-queue lookahead slots

    const int tid  = threadIdx.x;
    const int lane = tid & 63;
    const int wid  = tid >> 6;    // 0..7
    const int half = lane >> 5;   // 0: even node of pair, 1: odd
    const int q    = lane & 31;   // owns dims 4q..4q+3
    const int nl   = lane & 15;
    const int kb   = lane >> 4;
    const int r0   = wid * 2;     // this wave's 2 rows in each tile

    // ---- A-fragments for nt=wid in registers (W gathered once; same RNE) ----
    bfrag a[4];
    #pragma unroll
    for (int kc = 0; kc < 4; ++kc)
        #pragma unroll
        for (int i = 0; i < 8; ++i) {
            const int k = kc * 32 + kb * 8 + i;
            a[kc][i] = (short)f2bf(W[k * DOUT + wid * 16 + nl]);
        }

    // ---- queue prologue: fetch s0, s1 ----
    if (tid == 0) {
        sQ[0] = atomicAdd(qcnt, 1);
        sQ[1] = atomicAdd(qcnt, 1);
    }
    __syncthreads();
    int s_cur = sQ[0];
    int s_nxt = sQ[1];

    f32x4 v[K], sv;               // packed: this lane's node

    if (s_cur < n_stiles) {       // prologue loads: (s_cur, tile 0) pair
        const int n0 = s_cur * 32 + r0 + half;
        const float* nb = neigh_vecs + (size_t)n0 * (K * D) + 4 * q;
        #pragma unroll
        for (int k = 0; k < K; ++k) v[k] = nt_load4(nb + k * D);
        sv = nt_load4(self_vecs + (size_t)n0 * D + 4 * q);
    }

    int buf = 0, r = 0;
    while (s_cur < n_stiles) {
        // ---- 2 ctx pairs; refills: tt=0 loads (s_cur,t1), tt=1 loads (s_nxt,t0) ----
        #pragma unroll
        for (int tt = 0; tt < 2; ++tt) {
            int rs, rt;                          // refill target
            if (tt == 0) { rs = s_cur; rt = 1; }
            else {
                rs = (s_nxt < n_stiles) ? s_nxt : s_cur;  // clamped (branch-free)
                rt = 0;
            }
            const int rn = (rs * 2 + rt) * 16 + r0 + half;
            const float* nbN = neigh_vecs + (size_t)rn * (K * D) + 4 * q;

            // single-pass softmax+context, shift m = ss (exact by invariance)
            float ss = half_allsum(sv.x * sv.x + sv.y * sv.y + sv.z * sv.z + sv.w * sv.w);
            float sum = 1.f;                     // self term: exp(ss-ss)=1
            f32x4 cx = sv;
            #pragma unroll
            for (int k = 0; k < K; ++k) {
                float p = sv.x * v[k].x + sv.y * v[k].y + sv.z * v[k].z + sv.w * v[k].w;
                p = half_allsum(p);
                const float e = __expf(p - ss);
                sum += e;
                cx.x += e * v[k].x; cx.y += e * v[k].y;
                cx.z += e * v[k].z; cx.w += e * v[k].w;
                v[k] = nt_load4(nbN + k * D);    // last use -> NT refill in place
            }
            sv = nt_load4(self_vecs + (size_t)rn * D + 4 * q);

            const float inv = 1.f / sum;
            const float cf[4] = {cx.x * inv, cx.y * inv, cx.z * inv, cx.w * inv};
            unsigned short hi4[4], lo4[4];
            #pragma unroll
            for (int i = 0; i < 4; ++i) {
                hi4[i] = f2bf(cf[i]);
                lo4[i] = f2bf(cf[i] - bf2f(hi4[i]));
            }
            *(uint2*)&Chl[buf][tt][0][r0 + half][4 * q] = *(const uint2*)hi4;
            *(uint2*)&Chl[buf][tt][1][r0 + half][4 * q] = *(const uint2*)lo4;
        }

        // ---- fetch s_{r+2} (published by the barrier below) ----
        if (tid == 0) sQ[r & 1] = atomicAdd(qcnt, 1);

        __syncthreads();   // publishes Chl[buf] AND sQ[r&1]

        // ---- MFMA: both tiles of s_cur, A from registers; nt = wid ----
        #pragma unroll
        for (int tt = 0; tt < 2; ++tt) {
            afrag acc;
            #pragma unroll
            for (int r4 = 0; r4 < 4; ++r4) acc[r4] = 0.f;
            #pragma unroll
            for (int kc = 0; kc < 4; ++kc) {
                const bfrag ch = *(const bfrag*)&Chl[buf][tt][0][nl][kc * 32 + kb * 8];
                const bfrag cl = *(const bfrag*)&Chl[buf][tt][1][nl][kc * 32 + kb * 8];
                acc = __builtin_amdgcn_mfma_f32_16x16x32_bf16(a[kc], ch, acc, 0, 0, 0);
                acc = __builtin_amdgcn_mfma_f32_16x16x32_bf16(a[kc], cl, acc, 0, 0, 0);
            }
            // D: col=lane&15=node, row=(lane>>4)*4+r=outcol (m89-verified)
            const int node0t = (s_cur * 2 + tt) * 16;
            float* orow = out + (size_t)(node0t + nl) * DOUT + kb * 4;
            f32x4 res;
            res.x = fmaxf(acc[0], 0.f); res.y = fmaxf(acc[1], 0.f);
            res.z = fmaxf(acc[2], 0.f); res.w = fmaxf(acc[3], 0.f);
            __builtin_nontemporal_store(res, (f32x4*)(orow + wid * 16));
        }

        s_cur = s_nxt;
        s_nxt = sQ[r & 1];   // read after barrier (safe)
        buf ^= 1; ++r;
    }
}

extern "C" void kernel_launch(void* const* d_in, const int* in_sizes, int n_in,
                              void* d_out, int out_size, void* d_ws, size_t ws_size,
                              hipStream_t stream) {
    const float* self_vecs = (const float*)d_in[0];
    const float* neigh     = (const float*)d_in[1];
    const float* W         = (const float*)d_in[2];
    float* out = (float*)d_out;
    int* qcnt  = (int*)d_ws;

    const int n_nodes  = in_sizes[0] / D;   // 100000
    const int n_stiles = n_nodes / 32;      // 3125 exact

    // reset the work-queue counter (async memset is graph-capture-safe;
    // the harness itself enqueues hipMemsetAsync on this stream)
    hipMemsetAsync(qcnt, 0, sizeof(int), stream);

    const int tpb = 512;     // 8 waves
    const int blocks = 512;  // 2 blocks/CU x 256 CU (68 KiB LDS each)
    gat_fused<<<dim3(blocks), dim3(tpb), 0, stream>>>(
        self_vecs, neigh, W, out, n_stiles, qcnt);
}

// Round 26
// 172.363 us; speedup vs baseline: 1.0444x; 1.0444x over previous
//
#include <hip/hip_runtime.h>

// GAT aggregate, FUSED (R26 = R24 exact revert; R25's dynamic queue regressed
// 172.6 -> 180.0): N=100000, K=16, D=128, DOUT=128, fp32.
// Per round, one 512-thr block (8 waves) processes TWO 16-node tiles: each
// wave runs 2 lane-packed ctx pairs (node A lanes 0-31 / node B 32-63,
// float4/lane, single-pass softmax with exact shift m=|self|^2, NT in-loop
// v-refills streaming HBM through compute), writes bf16 hi/lo rows to dbuf
// LDS, ONE barrier per 32 nodes, then MFMA for both tiles with A-fragments
// in registers (nt=wid; W gathered once, Wt LDS deleted).
//
// Status: 5.34 TB/s effective = 85% of measured copy ceiling (m13 6.29);
// pace is L3-invariant (R15) and schedule-invariant (R14-R25) -> per-CU
// read-path ceiling. NT ops (+3.6%) was the last working lever.

constexpr int K    = 16;
constexpr int D    = 128;
constexpr int DOUT = 128;
constexpr int CT_PITCH = 136;   // bf16 pitch (shorts), 272B rows

typedef short bfrag  __attribute__((ext_vector_type(8)));
typedef float afrag  __attribute__((ext_vector_type(4)));
typedef float f32x4  __attribute__((ext_vector_type(4)));   // NT-compatible 16B vector

__device__ __forceinline__ unsigned short f2bf(float f) {
    union { float f; unsigned u; } v; v.f = f;
    const unsigned r = v.u + 0x7FFF + ((v.u >> 16) & 1);   // RNE
    return (unsigned short)(r >> 16);
}
__device__ __forceinline__ float bf2f(unsigned short b) {
    union { unsigned u; float f; } v; v.u = ((unsigned)b) << 16;
    return v.f;
}

__device__ __forceinline__ f32x4 nt_load4(const float* p) {
    return __builtin_nontemporal_load((const f32x4*)p);
}

// 5-hop butterfly allreduce WITHIN each 32-lane half (off<=16 stays in-half)
__device__ __forceinline__ float half_allsum(float x) {
    #pragma unroll
    for (int off = 1; off <= 16; off <<= 1)
        x += __shfl_xor(x, off);
    return x;
}

__launch_bounds__(512, 2)
__global__ void gat_fused(const float* __restrict__ self_vecs,
                          const float* __restrict__ neigh_vecs,
                          const float* __restrict__ W,
                          float* __restrict__ out,
                          int n_stiles) {
    // [buf][tile][plane hi/lo][row][k]  = 68 KiB; the ONLY LDS
    __shared__ __align__(16) unsigned short Chl[2][2][2][16][CT_PITCH];

    const int tid  = threadIdx.x;
    const int lane = tid & 63;
    const int wid  = tid >> 6;    // 0..7
    const int half = lane >> 5;   // 0: even node of pair, 1: odd
    const int q    = lane & 31;   // owns dims 4q..4q+3
    const int nl   = lane & 15;
    const int kb   = lane >> 4;
    const int r0   = wid * 2;     // this wave's 2 rows in each tile

    // ---- A-fragments for nt=wid in registers (W gathered once; same RNE) ----
    bfrag a[4];
    #pragma unroll
    for (int kc = 0; kc < 4; ++kc)
        #pragma unroll
        for (int i = 0; i < 8; ++i) {
            const int k = kc * 32 + kb * 8 + i;
            a[kc][i] = (short)f2bf(W[k * DOUT + wid * 16 + nl]);
        }

    f32x4 v[K], sv;               // packed: this lane's node

    int buf = 0;
    int st = blockIdx.x;

    if (st < n_stiles) {          // prologue: (st, tile 0) pair in flight
        const int n0 = st * 32 + r0 + half;
        const float* nb = neigh_vecs + (size_t)n0 * (K * D) + 4 * q;
        #pragma unroll
        for (int k = 0; k < K; ++k) v[k] = nt_load4(nb + k * D);
        sv = nt_load4(self_vecs + (size_t)n0 * D + 4 * q);
    }

    for (; st < n_stiles; st += gridDim.x, buf ^= 1) {
        // ---- 2 ctx pairs; refill streams: tt=0 loads tt=1, tt=1 loads next st ----
        #pragma unroll
        for (int tt = 0; tt < 2; ++tt) {
            int rs, rt;                          // refill target
            if (tt == 0) { rs = st; rt = 1; }
            else {
                const int sn = st + gridDim.x;
                rs = (sn < n_stiles) ? sn : st;  // clamped (branch-free tail)
                rt = 0;
            }
            const int rn = (rs * 2 + rt) * 16 + r0 + half;
            const float* nbN = neigh_vecs + (size_t)rn * (K * D) + 4 * q;

            // single-pass softmax+context, shift m = ss (exact by invariance)
            float ss = half_allsum(sv.x * sv.x + sv.y * sv.y + sv.z * sv.z + sv.w * sv.w);
            float sum = 1.f;                     // self term: exp(ss-ss)=1
            f32x4 cx = sv;
            #pragma unroll
            for (int k = 0; k < K; ++k) {
                float p = sv.x * v[k].x + sv.y * v[k].y + sv.z * v[k].z + sv.w * v[k].w;
                p = half_allsum(p);
                const float e = __expf(p - ss);
                sum += e;
                cx.x += e * v[k].x; cx.y += e * v[k].y;
                cx.z += e * v[k].z; cx.w += e * v[k].w;
                v[k] = nt_load4(nbN + k * D);    // last use -> NT refill in place
            }
            sv = nt_load4(self_vecs + (size_t)rn * D + 4 * q);

            const float inv = 1.f / sum;
            const float cf[4] = {cx.x * inv, cx.y * inv, cx.z * inv, cx.w * inv};
            unsigned short hi4[4], lo4[4];
            #pragma unroll
            for (int i = 0; i < 4; ++i) {
                hi4[i] = f2bf(cf[i]);
                lo4[i] = f2bf(cf[i] - bf2f(hi4[i]));
            }
            *(uint2*)&Chl[buf][tt][0][r0 + half][4 * q] = *(const uint2*)hi4;
            *(uint2*)&Chl[buf][tt][1][r0 + half][4 * q] = *(const uint2*)lo4;
        }

        __syncthreads();   // ONE barrier per 32 nodes (dbuf Chl)

        // ---- MFMA: both tiles, A from registers; this wave does nt = wid ----
        #pragma unroll
        for (int tt = 0; tt < 2; ++tt) {
            afrag acc;
            #pragma unroll
            for (int r4 = 0; r4 < 4; ++r4) acc[r4] = 0.f;
            #pragma unroll
            for (int kc = 0; kc < 4; ++kc) {
                const bfrag ch = *(const bfrag*)&Chl[buf][tt][0][nl][kc * 32 + kb * 8];
                const bfrag cl = *(const bfrag*)&Chl[buf][tt][1][nl][kc * 32 + kb * 8];
                acc = __builtin_amdgcn_mfma_f32_16x16x32_bf16(a[kc], ch, acc, 0, 0, 0);
                acc = __builtin_amdgcn_mfma_f32_16x16x32_bf16(a[kc], cl, acc, 0, 0, 0);
            }
            // D: col=lane&15=node, row=(lane>>4)*4+r=outcol (m89-verified)
            const int node0t = (st * 2 + tt) * 16;
            float* orow = out + (size_t)(node0t + nl) * DOUT + kb * 4;
            f32x4 res;
            res.x = fmaxf(acc[0], 0.f); res.y = fmaxf(acc[1], 0.f);
            res.z = fmaxf(acc[2], 0.f); res.w = fmaxf(acc[3], 0.f);
            __builtin_nontemporal_store(res, (f32x4*)(orow + wid * 16));
        }
    }
}

extern "C" void kernel_launch(void* const* d_in, const int* in_sizes, int n_in,
                              void* d_out, int out_size, void* d_ws, size_t ws_size,
                              hipStream_t stream) {
    const float* self_vecs = (const float*)d_in[0];
    const float* neigh     = (const float*)d_in[1];
    const float* W         = (const float*)d_in[2];
    float* out = (float*)d_out;

    const int n_nodes  = in_sizes[0] / D;   // 100000
    const int n_stiles = n_nodes / 32;      // 3125 exact

    const int tpb = 512;     // 8 waves
    const int blocks = 512;  // 2 blocks/CU x 256 CU (68 KiB LDS each) -> 16 waves/CU
    gat_fused<<<dim3(blocks), dim3(tpb), 0, stream>>>(
        self_vecs, neigh, W, out, n_stiles);
}